// Round 1
// baseline (949.773 us; speedup 1.0000x reference)
//
#include <hip/hip_runtime.h>
#include <hip/hip_bf16.h>
#include <math.h>

// Problem constants
//   H=4 heads, S=128 seq, D=32 head dim, B=64 batch, SD=S*D=4096
//   x: [B, S, H*D] fp32; W*: [H, SD, SD] fp32 (row = out, col = in); b*: [H, SD]
//   out: [B, S, H*D] fp32
// Pipeline:
//   1) qkv_gemm: Q/K/V[h,b,o] = sum_i xh[h,b,i]*W[h,o,i] + b[h,o]  -> ws
//   2) attn: per (h,b): scores=Q*K^T (S x S), causal mask (k>q -> -inf),
//      softmax over the *query* axis (column-wise), Z = P*V / sqrt(D)

#define NH 4
#define NS 128
#define ND 32
#define NB 64
#define NSD 4096            // S*D
#define XROW 16384          // S*H*D = per-batch stride in x
#define HBSD (NH * NB * NSD)

// ---------------------------------------------------------------------------
// GEMM: tile 64(b) x 64(o), K-tile 64. LDS layouts transposed: [k][row],
// stride 68 floats so ds_read_b128 along rows hits distinct banks.
// Thread: b = (tid>>4)*4 + i, o = (tid&15)*4 + j -> 16 accumulators.
// ---------------------------------------------------------------------------
__global__ __launch_bounds__(256)
void qkv_gemm(const float* __restrict__ x,
              const float* __restrict__ Wq, const float* __restrict__ bq,
              const float* __restrict__ Wk, const float* __restrict__ bk,
              const float* __restrict__ Wv, const float* __restrict__ bv,
              float* __restrict__ Qo, float* __restrict__ Ko, float* __restrict__ Vo)
{
    const int ot = blockIdx.x;       // o-tile index, 64 cols each
    const int h  = blockIdx.y;       // head
    const int pz = blockIdx.z;       // 0=Q 1=K 2=V

    const float* W; const float* bias; float* out;
    if (pz == 0)      { W = Wq; bias = bq; out = Qo; }
    else if (pz == 1) { W = Wk; bias = bk; out = Ko; }
    else              { W = Wv; bias = bv; out = Vo; }
    W    += (size_t)h * NSD * NSD;
    bias += (size_t)h * NSD;
    out  += (size_t)h * NB * NSD;

    __shared__ float Xs[64][68];     // [k][b]
    __shared__ float Ws[64][68];     // [k][o]

    const int tid = threadIdx.x;
    const int o0  = ot * 64;
    const float* xh = x + h * ND;    // xh(b,k) = x[b*XROW + (k>>5)*128 + h*32 + (k&31)]

    const int bg = tid >> 4;         // 0..15  (b group)
    const int og = tid & 15;         // 0..15  (o group)

    float acc[4][4] = {};

    for (int k0 = 0; k0 < NSD; k0 += 64) {
        // --- stage tiles (each thread: 4 float4 of X, 4 float4 of W) ---
        #pragma unroll
        for (int i = 0; i < 4; ++i) {
            const int f  = tid + i * 256;   // float4 id 0..1023
            const int rr = f >> 4;          // row (b or o), 0..63
            const int kq = f & 15;          // float4 index along k
            const int k  = k0 + kq * 4;

            const float4 xv = *(const float4*)(xh + (size_t)rr * XROW + (k >> 5) * 128 + (k & 31));
            Xs[kq*4+0][rr] = xv.x;
            Xs[kq*4+1][rr] = xv.y;
            Xs[kq*4+2][rr] = xv.z;
            Xs[kq*4+3][rr] = xv.w;

            const float4 wv = *(const float4*)(W + (size_t)(o0 + rr) * NSD + k);
            Ws[kq*4+0][rr] = wv.x;
            Ws[kq*4+1][rr] = wv.y;
            Ws[kq*4+2][rr] = wv.z;
            Ws[kq*4+3][rr] = wv.w;
        }
        __syncthreads();

        // --- outer-product accumulation over this K-tile ---
        #pragma unroll 8
        for (int k = 0; k < 64; ++k) {
            const float4 xv = *(const float4*)&Xs[k][bg * 4];
            const float4 wv = *(const float4*)&Ws[k][og * 4];
            const float xa[4] = {xv.x, xv.y, xv.z, xv.w};
            const float wa[4] = {wv.x, wv.y, wv.z, wv.w};
            #pragma unroll
            for (int i = 0; i < 4; ++i)
                #pragma unroll
                for (int j = 0; j < 4; ++j)
                    acc[i][j] += xa[i] * wa[j];
        }
        __syncthreads();
    }

    // --- epilogue: + bias, store float4 ---
    const int b0  = bg * 4;
    const int oc0 = o0 + og * 4;
    const float4 bb = *(const float4*)(bias + oc0);
    #pragma unroll
    for (int i = 0; i < 4; ++i) {
        float4 r;
        r.x = acc[i][0] + bb.x;
        r.y = acc[i][1] + bb.y;
        r.z = acc[i][2] + bb.z;
        r.w = acc[i][3] + bb.w;
        *(float4*)(out + (size_t)(b0 + i) * NSD + oc0) = r;
    }
}

// ---------------------------------------------------------------------------
// Attention: one block per (h,b). K,V,P staged in LDS; Q rows in registers.
// scores[q][k] for all pairs; softmax normalizes each COLUMN k over q>=k
// (reference uses softmax over the query axis); invalid entries zeroed so
// the PV loop is uniform (no divergence); Z scaled by 1/sqrt(D).
// ---------------------------------------------------------------------------
__global__ __launch_bounds__(256)
void attn_kernel(const float* __restrict__ Qg, const float* __restrict__ Kg,
                 const float* __restrict__ Vg, float* __restrict__ out)
{
    const int h = blockIdx.x >> 6;
    const int b = blockIdx.x & 63;
    const float* Qhb = Qg + (size_t)(h * NB + b) * NSD;   // [128][32]
    const float* Khb = Kg + (size_t)(h * NB + b) * NSD;
    const float* Vhb = Vg + (size_t)(h * NB + b) * NSD;

    __shared__ float Ks[128][32];
    __shared__ float Vs[128][32];
    __shared__ float P[128][129];    // pad -> conflict-free column access

    const int tid = threadIdx.x;

    // --- stage K, V ---
    #pragma unroll
    for (int i = 0; i < 4; ++i) {
        const int f = tid + i * 256;     // float4 id 0..1023
        const int r = f >> 3;            // row 0..127
        const int c = (f & 7) * 4;
        *(float4*)&Ks[r][c] = *(const float4*)(Khb + r * ND + c);
        *(float4*)&Vs[r][c] = *(const float4*)(Vhb + r * ND + c);
    }

    // --- my two Q rows into registers ---
    const int q0 = tid & 63;             // rows q0 and q0+64
    const int kq = tid >> 6;             // k-quarter 0..3
    float4 qa[8], qb[8];
    #pragma unroll
    for (int i = 0; i < 8; ++i) {
        qa[i] = *(const float4*)(Qhb + q0 * ND + i * 4);
        qb[i] = *(const float4*)(Qhb + (q0 + 64) * ND + i * 4);
    }
    __syncthreads();

    // --- scores: each thread covers 2 q-rows x 32 k's ---
    for (int kk = kq * 32; kk < kq * 32 + 32; ++kk) {
        float sa = 0.f, sb = 0.f;
        #pragma unroll
        for (int i = 0; i < 8; ++i) {
            const float4 kv = *(const float4*)&Ks[kk][i * 4];
            sa += qa[i].x * kv.x + qa[i].y * kv.y + qa[i].z * kv.z + qa[i].w * kv.w;
            sb += qb[i].x * kv.x + qb[i].y * kv.y + qb[i].z * kv.z + qb[i].w * kv.w;
        }
        P[q0][kk]      = sa;
        P[q0 + 64][kk] = sb;
    }
    __syncthreads();

    // --- column softmax over q (valid region q >= k), two threads/column ---
    {
        const int k    = tid >> 1;
        const int half = tid & 1;
        float m = -INFINITY;
        for (int q = half; q < 128; q += 2)
            if (q >= k) m = fmaxf(m, P[q][k]);
        m = fmaxf(m, __shfl_xor(m, 1));

        float s = 0.f;
        for (int q = half; q < 128; q += 2) {
            const float e = (q >= k) ? __expf(P[q][k] - m) : 0.f;
            P[q][k] = e;                 // invalid entries zeroed
            s += e;
        }
        s += __shfl_xor(s, 1);
        const float inv = 1.f / s;
        for (int q = half; q < 128; q += 2)
            P[q][k] *= inv;
    }
    __syncthreads();

    // --- Z = P @ V * (1/sqrt(D)); thread: q = tid&127, d-half = (tid>>7)*16 ---
    const int q  = tid & 127;
    const int dh = (tid >> 7) * 16;
    float acc[16] = {};
    for (int k = 0; k < 128; ++k) {
        const float p = P[q][k];
        #pragma unroll
        for (int i = 0; i < 4; ++i) {
            const float4 vv = *(const float4*)&Vs[k][dh + i * 4];
            acc[i*4+0] += p * vv.x;
            acc[i*4+1] += p * vv.y;
            acc[i*4+2] += p * vv.z;
            acc[i*4+3] += p * vv.w;
        }
    }
    const float sc = 0.17677669529663687f;   // 1/sqrt(32)
    float* op = out + (size_t)b * XROW + (size_t)q * (NH * ND) + h * ND + dh;
    #pragma unroll
    for (int i = 0; i < 4; ++i) {
        float4 r;
        r.x = acc[i*4+0] * sc;
        r.y = acc[i*4+1] * sc;
        r.z = acc[i*4+2] * sc;
        r.w = acc[i*4+3] * sc;
        *(float4*)(op + i * 4) = r;
    }
}

// ---------------------------------------------------------------------------
extern "C" void kernel_launch(void* const* d_in, const int* in_sizes, int n_in,
                              void* d_out, int out_size, void* d_ws, size_t ws_size,
                              hipStream_t stream)
{
    const float* x  = (const float*)d_in[0];
    const float* WQ = (const float*)d_in[1];
    const float* bQ = (const float*)d_in[2];
    const float* WK = (const float*)d_in[3];
    const float* bK = (const float*)d_in[4];
    const float* WV = (const float*)d_in[5];
    const float* bV = (const float*)d_in[6];
    float* out = (float*)d_out;

    float* Qw = (float*)d_ws;            // [H, B, SD] each, 4 MB apiece
    float* Kw = Qw + HBSD;
    float* Vw = Kw + HBSD;

    dim3 g1(NSD / 64, NH, 3);            // 64 o-tiles x 4 heads x {Q,K,V}
    qkv_gemm<<<g1, 256, 0, stream>>>(x, WQ, bQ, WK, bK, WV, bV, Qw, Kw, Vw);

    attn_kernel<<<dim3(NH * NB), 256, 0, stream>>>(Qw, Kw, Vw, out);
}